// Round 6
// baseline (15.860 us; speedup 1.0000x reference)
//
#include <hip/hip_runtime.h>
#include <math.h>

#define H_DIM 512
#define N_DIM 32
#define L_LEN 1024

typedef float v2f __attribute__((ext_vector_type(2)));
__device__ __forceinline__ v2f splat2(float a) { return (v2f){a, a}; }

// DIF radix-2 inverse FFT, executed as radix-4 stage pairs.
// Butterfly twiddle W(s, r) = e^{+i*pi*r/s}. Thread t ends holding y[bitrev9(t)].

__launch_bounds__(576, 5)
__global__ void ssk_nplr_kernel(const float* __restrict__ log_dt,
                                const float* __restrict__ inv_w_real,
                                const float* __restrict__ w_imag,
                                const float* __restrict__ B_ri,
                                const float* __restrict__ C_ri,
                                const float* __restrict__ P_ri,
                                float* __restrict__ out)
{
    __shared__ float2 Ksh[513];
    __shared__ float2 polD[N_DIM];   // {-2*Re(w*dt), |w*dt|^2}
    __shared__ float4 polA[N_DIM];   // a00,a01,a10,a11  (numer = a*z - b)
    __shared__ float4 polB[N_DIM];   // b00,b01,b10,b11
    __shared__ float  Sre[512], Sim[512];

    const int t = threadIdx.x;
    const int h = blockIdx.x;
    const float dt = expf(log_dt[h]);

    // ---------------- Phase A: per-h pole coefficients ----------------
    if (t < N_DIM) {
        const int n = t;
        float wr = -expf(inv_w_real[n]);   // S=1
        float wi = w_imag[n];
        float wdx = wr * dt, wdy = wi * dt;
        float Bx = B_ri[2*n],               By = B_ri[2*n+1];
        float Cx = C_ri[h*2*N_DIM + 2*n],   Cy = C_ri[h*2*N_DIM + 2*n+1];
        float Px = P_ri[2*n],               Py = P_ri[2*n+1];
        float v00x = Bx*Cx - By*Cy, v00y = Bx*Cy + By*Cx;   // B*C
        float v01x = Bx*Px + By*Py, v01y = By*Px - Bx*Py;   // B*conj(P)
        float v10x = Px*Cx - Py*Cy, v10y = Px*Cy + Py*Cx;   // P*C
        float v11x = Px*Px + Py*Py;                         // |P|^2
        polD[n] = make_float2(-2.0f*wdx, wdx*wdx + wdy*wdy);
        polA[n] = make_float4(2.0f*v00x, 2.0f*v01x, 2.0f*v10x, 2.0f*v11x);
        polB[n] = make_float4(2.0f*(v00x*wdx + v00y*wdy),
                              2.0f*(v01x*wdx + v01y*wdy),
                              2.0f*(v10x*wdx + v10y*wdy),
                              2.0f*(v11x*wdx));             // v11y = 0
    }

    // ---------------- Twiddle precompute (data-independent; hides under
    // Phase A global-load latency and Phase B LDS bubbles) ----------------
    // W(s, r) = e^{+i pi r/s}; hw sin/cos take revolutions -> rev = r/(2s).
    float w256c, w256s, w128c, w128s, w64c, w64s;
    float w32c, w32s, w16c, w16s, w8c, w8s, w4c, w4s;
    {
        float r256 = (float)(t & 255) * (1.0f/512.0f);
        float r128 = (float)(t & 127) * (1.0f/256.0f);
        float r64  = (float)(t &  63) * (1.0f/128.0f);
        float r32  = (float)(t &  31) * (1.0f/64.0f);
        float r16  = (float)(t &  15) * (1.0f/32.0f);
        float r8   = (float)(t &   7) * (1.0f/16.0f);
        float r4   = (float)(t &   3) * (1.0f/8.0f);
        w256s = __builtin_amdgcn_sinf(r256); w256c = __builtin_amdgcn_cosf(r256);
        w128s = __builtin_amdgcn_sinf(r128); w128c = __builtin_amdgcn_cosf(r128);
        w64s  = __builtin_amdgcn_sinf(r64);  w64c  = __builtin_amdgcn_cosf(r64);
        w32s  = __builtin_amdgcn_sinf(r32);  w32c  = __builtin_amdgcn_cosf(r32);
        w16s  = __builtin_amdgcn_sinf(r16);  w16c  = __builtin_amdgcn_cosf(r16);
        w8s   = __builtin_amdgcn_sinf(r8);   w8c   = __builtin_amdgcn_cosf(r8);
        w4s   = __builtin_amdgcn_sinf(r4);   w4c   = __builtin_amdgcn_cosf(r4);
    }

    // omega = e^{-2pi i j/1024}; j=512 emulates numpy's sinf(-pi_f32) (NaN guard).
    const int j = (t < 512) ? t : 512;
    float si, co;
    if (j == 512) {
        si = 8.7422777e-8f;
        co = -1.0f;
    } else {
        float rev = (float)j * (-0.0009765625f);           // -j/1024 revolutions
        si = __builtin_amdgcn_sinf(rev);
        co = __builtin_amdgcn_cosf(rev);
    }
    __syncthreads();

    // ---------------- Phase B: k_f[j] ----------------
    float px = 1.0f + co, py = si;                         // 1 + omega
    float pinv = 1.0f / (px*px + py*py);
    float ipx = px*pinv, ipy = -py*pinv;                   // 1/(1+omega)
    float mx = 1.0f - co, my = -si;                        // 1 - omega
    float zx = 2.0f*(mx*ipx - my*ipy);                     // z = 2(1-w)/(1+w)
    float zy = 2.0f*(mx*ipy + my*ipx);

    v2f Z  = { zx, zy };
    v2f Z2 = { zx*zx - zy*zy, 2.0f*zx*zy };

    v2f U0{0,0}, U1{0,0}, U2{0,0}, U3{0,0};
    v2f V0{0,0}, V1{0,0}, V2{0,0}, V3{0,0};
    #pragma unroll 4
    for (int n = 0; n < N_DIM; ++n) {
        float2 d  = polD[n];
        float4 A  = polA[n];
        float4 Bv = polB[n];
        v2f D = __builtin_elementwise_fma(splat2(d.x), Z, Z2);
        D.x += d.y;
        float s  = __builtin_amdgcn_rcpf(fmaf(D.x, D.x, D.y*D.y));
        v2f R = { D.x * s, -(D.y * s) };                   // 1/D
        U0 = __builtin_elementwise_fma(splat2(A.x),  R, U0);
        U1 = __builtin_elementwise_fma(splat2(A.y),  R, U1);
        U2 = __builtin_elementwise_fma(splat2(A.z),  R, U2);
        U3 = __builtin_elementwise_fma(splat2(A.w),  R, U3);
        V0 = __builtin_elementwise_fma(splat2(Bv.x), R, V0);
        V1 = __builtin_elementwise_fma(splat2(Bv.y), R, V1);
        V2 = __builtin_elementwise_fma(splat2(Bv.z), R, V2);
        V3 = __builtin_elementwise_fma(splat2(Bv.w), R, V3);
    }
    float r00x = dt*(zx*U0.x - zy*U0.y - V0.x), r00y = dt*(zx*U0.y + zy*U0.x - V0.y);
    float r01x = dt*(zx*U1.x - zy*U1.y - V1.x), r01y = dt*(zx*U1.y + zy*U1.x - V1.y);
    float r10x = dt*(zx*U2.x - zy*U2.y - V2.x), r10y = dt*(zx*U2.y + zy*U2.x - V2.y);
    float r11x = dt*(zx*U3.x - zy*U3.y - V3.x), r11y = dt*(zx*U3.y + zy*U3.x - V3.y);

    float dnx = 1.0f + r11x, dny = r11y;
    float dinv = 1.0f / (dnx*dnx + dny*dny);
    float idx_ = dnx*dinv, idy = -dny*dinv;
    float m01x = r01x*r10x - r01y*r10y;
    float m01y = r01x*r10y + r01y*r10x;
    float kfx = r00x - (m01x*idx_ - m01y*idy);
    float kfy = r00y - (m01x*idy + m01y*idx_);
    float fxv = 2.0f*(kfx*ipx - kfy*ipy);
    float fyv = 2.0f*(kfx*ipy + kfy*ipx);
    if (t <= 512) Ksh[j] = make_float2(fxv, fyv);
    __syncthreads();

    // ---------------- Phase C: irfft via packed complex IFFT(512) ----------------
    float xr = 0.0f, xi = 0.0f;
    if (t < 512) {
        // Hermitian -> complex packing fused with the s=256 butterfly.
        float2 Ka = Ksh[t];
        float2 Kb = Ksh[512 - t];
        const int tb = t ^ 256;
        float2 Kc = Ksh[tb];
        float2 Kd = Ksh[512 - tb];
        float Wx = co, Wy = -si;                   // e^{+2pi i t/1024}
        float hsx = 0.5f*(Ka.x + Kb.x), hsy = 0.5f*(Ka.y - Kb.y);
        float hdx = 0.5f*(Ka.x - Kb.x), hdy = 0.5f*(Ka.y + Kb.y);
        float Yax = hsx - Wy*hdx - Wx*hdy;
        float Yay = hsy - Wy*hdy + Wx*hdx;
        float Wbx = (t < 256) ? -Wy :  Wy;         // e^{+2pi i (t^256)/1024}
        float Wby = (t < 256) ?  Wx : -Wx;
        float hsx2 = 0.5f*(Kc.x + Kd.x), hsy2 = 0.5f*(Kc.y - Kd.y);
        float hdx2 = 0.5f*(Kc.x - Kd.x), hdy2 = 0.5f*(Kc.y + Kd.y);
        float Ybx = hsx2 - Wby*hdx2 - Wbx*hdy2;
        float Yby = hsy2 - Wby*hdy2 + Wbx*hdx2;
        if (t & 256) {
            float dr = Ybx - Yax, di = Yby - Yay;
            xr = dr*w256c - di*w256s; xi = dr*w256s + di*w256c;
        } else {
            xr = Yax + Ybx; xi = Yay + Yby;
        }
        Sre[t] = xr; Sim[t] = xi;
    }
    __syncthreads();

    if (t < 512) {
        // ---- radix-4 pair (128, 64) via one LDS round ----
        {
            float p1r = Sre[t ^ 128], p1i = Sim[t ^ 128];
            float p2r = Sre[t ^  64], p2i = Sim[t ^  64];
            float p3r = Sre[t ^ 192], p3i = Sim[t ^ 192];
            float Atr, Ati, Apr, Api;
            if (t & 128) {
                float dr = p1r - xr, di = p1i - xi;
                Atr = dr*w128c - di*w128s; Ati = dr*w128s + di*w128c;
                float er = p3r - p2r, ei = p3i - p2i;
                float wpr = (t & 64) ?  w128s : -w128s;   // -i*W1 : +i*W1
                float wpi = (t & 64) ? -w128c :  w128c;
                Apr = er*wpr - ei*wpi; Api = er*wpi + ei*wpr;
            } else {
                Atr = xr + p1r;  Ati = xi + p1i;
                Apr = p2r + p3r; Api = p2i + p3i;
            }
            if (t & 64) {
                float dr = Apr - Atr, di = Api - Ati;
                xr = dr*w64c - di*w64s; xi = dr*w64s + di*w64c;
            } else { xr = Atr + Apr; xi = Ati + Api; }
        }

        // ---- radix-4 pairs via 3 independent shfls each ----
        #define RADIX4S(S_, W1C, W1S, W2C, W2S) {                               \
            float p1r = __shfl_xor(xr, S_),        p1i = __shfl_xor(xi, S_);    \
            float p2r = __shfl_xor(xr, S_/2),      p2i = __shfl_xor(xi, S_/2);  \
            float p3r = __shfl_xor(xr, S_ + S_/2), p3i = __shfl_xor(xi, S_ + S_/2); \
            float Atr, Ati, Apr, Api;                                           \
            if (t & S_) {                                                       \
                float dr = p1r - xr, di = p1i - xi;                             \
                Atr = dr*W1C - di*W1S; Ati = dr*W1S + di*W1C;                   \
                float er = p3r - p2r, ei = p3i - p2i;                           \
                float wpr = (t & (S_/2)) ?  W1S : -W1S;                         \
                float wpi = (t & (S_/2)) ? -W1C :  W1C;                         \
                Apr = er*wpr - ei*wpi; Api = er*wpi + ei*wpr;                   \
            } else {                                                            \
                Atr = xr + p1r;  Ati = xi + p1i;                                \
                Apr = p2r + p3r; Api = p2i + p3i;                               \
            }                                                                   \
            if (t & (S_/2)) {                                                   \
                float dr = Apr - Atr, di = Api - Ati;                           \
                xr = dr*W2C - di*W2S; xi = dr*W2S + di*W2C;                     \
            } else { xr = Atr + Apr; xi = Ati + Api; }                          \
        }
        RADIX4S(32, w32c, w32s, w16c, w16s)
        RADIX4S(8,  w8c,  w8s,  w4c,  w4s)
        #undef RADIX4S

        // ---- final pair (2, 1): W in {1, i}, no trig ----
        {
            float p1r = __shfl_xor(xr, 2), p1i = __shfl_xor(xi, 2);
            float p2r = __shfl_xor(xr, 1), p2i = __shfl_xor(xi, 1);
            float p3r = __shfl_xor(xr, 3), p3i = __shfl_xor(xi, 3);
            float Atr, Ati, Apr, Api;
            if (t & 2) {
                float dr = p1r - xr, di = p1i - xi;
                float er = p3r - p2r, ei = p3i - p2i;
                if (t & 1) { Atr = -di; Ati =  dr;   // W1 = i
                             Apr =  er; Api =  ei; } // W1' = 1
                else       { Atr =  dr; Ati =  di;   // W1 = 1
                             Apr = -ei; Api =  er; } // W1' = i
            } else {
                Atr = xr + p1r;  Ati = xi + p1i;
                Apr = p2r + p3r; Api = p2i + p3i;
            }
            if (t & 1) { xr = Apr - Atr; xi = Api - Ati; }
            else       { xr = Atr + Apr; xi = Ati + Api; }
        }

        // thread t holds y[bitrev9(t)]; y[m] packs (x[2m], x[2m+1])
        unsigned m = __brev((unsigned)t) >> 23;
        ((float2*)out)[h*512 + m] = make_float2(xr*(1.0f/512.0f), xi*(1.0f/512.0f));
    }
}

extern "C" void kernel_launch(void* const* d_in, const int* in_sizes, int n_in,
                              void* d_out, int out_size, void* d_ws, size_t ws_size,
                              hipStream_t stream) {
    const float* log_dt     = (const float*)d_in[0];
    const float* inv_w_real = (const float*)d_in[1];
    const float* w_imag     = (const float*)d_in[2];
    const float* B_ri       = (const float*)d_in[3];
    const float* C_ri       = (const float*)d_in[4];
    const float* P_ri       = (const float*)d_in[5];
    // d_in[6] = L (constant 1024, baked in)

    ssk_nplr_kernel<<<H_DIM, 576, 0, stream>>>(log_dt, inv_w_real, w_imag,
                                               B_ri, C_ri, P_ri, (float*)d_out);
}